// Round 1
// baseline (371.519 us; speedup 1.0000x reference)
//
#include <hip/hip_runtime.h>
#include <cstdint>

// Problem constants
#define NB 32
#define IC 256
#define OC 256
#define H 56
#define WIDTH 56
#define OH 54
#define OW 54
#define HW (H*WIDTH)          // 3136
#define OHW (OH*OW)           // 2916
#define KTOT 2304             // 9 * 256, k = (kh*3+kw)*256 + c
#define M_TOT (NB*OHW)        // 93312

// GEMM tiling
#define BM 128                // spatial tile (D cols)
#define BO 128                // out-channel tile (D rows)
#define BK 32
#define KSTEPS (KTOT/BK)      // 72
#define MBLOCKS (M_TOT/BM)    // 729

// Static device scratch (avoids relying on ws_size):
// weights pre-tiled as the per-K-step LDS images: [ob(2)][step(72)][o'(128)][kc(32)] bf16 bits
__device__ __align__(16) unsigned short g_qwt[2*KSTEPS*BO*BK];
// x as NHWC bf16: [n][ih][iw][c]
__device__ __align__(16) unsigned short g_xq[NB*HW*IC];

typedef __bf16 bf16x8 __attribute__((ext_vector_type(8)));
typedef float  f32x4  __attribute__((ext_vector_type(4)));

__device__ inline unsigned short f32_bf16(float f) {
  union { float f; unsigned int u; } v; v.f = f;
  unsigned int u = v.u;
  return (unsigned short)((u + 0x7FFFu + ((u >> 16) & 1u)) >> 16);  // RNE
}

// ---- Kernel 1: binarize + pre-tile weights -------------------------------
// w layout: [o][c][kh][kw] fp32.  g_qwt[L], L linear over [ob][step][r][kc].
__global__ __launch_bounds__(256) void repack_w(const float* __restrict__ w) {
  int L = blockIdx.x * 256 + threadIdx.x;           // < 589824
  int ob  = (L >= KSTEPS*BO*BK) ? 1 : 0;
  int rem = L - ob*(KSTEPS*BO*BK);
  int step = rem >> 12;                             // /4096
  int r    = (rem >> 5) & 127;
  int kc   = rem & 31;
  int o = ob*BO + r;
  int k = step*BK + kc;
  int pos = k >> 8;                                 // kh*3+kw
  int c   = k & 255;
  int kh = pos / 3;
  int kw = pos - kh*3;
  float v = w[o*2304 + c*9 + kh*3 + kw];
  unsigned short s = (v > 0.f) ? 0x3F80u : ((v < 0.f) ? 0xBF80u : 0u);  // sign() in bf16
  g_qwt[L] = s;
}

// ---- Kernel 2: x NCHW fp32 -> NHWC bf16 ----------------------------------
__global__ __launch_bounds__(256) void xform_x(const float* __restrict__ x) {
  __shared__ unsigned short tile[256][66];          // pad +2: conflict-free transpose
  const int t   = threadIdx.x;
  const int n   = blockIdx.y;
  const int hw0 = blockIdx.x * 64;
  const int hwl = t & 63;
  const int cb  = t >> 6;                           // [0,4)
  for (int j = 0; j < 64; ++j) {
    int c = j*4 + cb;
    tile[c][hwl] = f32_bf16(x[(n*IC + c)*HW + hw0 + hwl]);   // coalesced fp32 reads
  }
  __syncthreads();
  for (int j = 0; j < 64; ++j) {
    g_xq[(n*HW + hw0 + j)*IC + t] = tile[t][j];              // coalesced 2B stores, bank-free
  }
}

// ---- Kernel 3: implicit-GEMM binary conv, D[o][m] ------------------------
// A-operand = weights (rows o), B-operand = im2col(x) (cols m).
__global__ __launch_bounds__(256) void bconv_gemm(float* __restrict__ out) {
  __shared__ __align__(16) unsigned short Wl[BO*BK];   // [o'][kc] 8 KB
  __shared__ __align__(16) unsigned short Xl[BM*BK];   // [m'][kc] 8 KB
  const int t  = threadIdx.x;
  const int m0 = blockIdx.x * BM;
  const int ob = blockIdx.y;

  // X staging: 512 16B-chunks per tile; thread t owns chunks t and t+256.
  // chunk q -> row i=q>>2 (m = m0+i), k-offset (q&3)*8. Spatial base fixed across K loop.
  int soff[2];
  #pragma unroll
  for (int hh = 0; hh < 2; ++hh) {
    int q = t + hh*256;
    int m = m0 + (q >> 2);
    int n  = m / OHW;
    int rm = m - n*OHW;
    int oh = rm / OW;
    int ow = rm - oh*OW;
    soff[hh] = ((n*H + oh)*WIDTH + ow)*IC + (q & 3)*8;
  }
  const unsigned short* wsrc = g_qwt + ob*(KSTEPS*BO*BK);

  const int lane = t & 63;
  const int wv   = t >> 6;
  const int col  = lane & 15;
  const int quad = lane >> 4;
  const int wo = (wv & 1) * 64;     // wave's o-offset in block tile
  const int wm = (wv >> 1) * 64;    // wave's m-offset in block tile
  int aoff[4], boff[4];
  #pragma unroll
  for (int i = 0; i < 4; ++i) {
    aoff[i] = (wo + i*16 + col)*BK + quad*8;   // A[m=lane&15][k=quad*8+j]
    boff[i] = (wm + i*16 + col)*BK + quad*8;   // B[k=quad*8+j][n=lane&15]
  }

  f32x4 acc[4][4];
  #pragma unroll
  for (int io = 0; io < 4; ++io)
    #pragma unroll
    for (int im = 0; im < 4; ++im)
      acc[io][im] = (f32x4){0.f, 0.f, 0.f, 0.f};

  for (int step = 0; step < KSTEPS; ++step) {
    const int k0  = step * BK;
    const int pos = k0 >> 8;           // uniform scalar
    const int c0  = k0 & 255;
    const int kh  = pos / 3;
    const int kw  = pos - kh*3;
    const int sk  = (kh*WIDTH + kw)*IC + c0;

    __syncthreads();
    // W tile: pure linear copy (pre-tiled in global)
    *(uint4*)(&Wl[t*8])         = *(const uint4*)(&wsrc[step*(BO*BK) + t*8]);
    *(uint4*)(&Wl[(t+256)*8])   = *(const uint4*)(&wsrc[step*(BO*BK) + (t+256)*8]);
    // X tile: im2col gather, 16B per chunk, 16B-aligned
    *(uint4*)(&Xl[t*8])         = *(const uint4*)(&g_xq[soff[0] + sk]);
    *(uint4*)(&Xl[(t+256)*8])   = *(const uint4*)(&g_xq[soff[1] + sk]);
    __syncthreads();

    bf16x8 av[4], bv[4];
    #pragma unroll
    for (int i = 0; i < 4; ++i) av[i] = *(const bf16x8*)(&Wl[aoff[i]]);
    #pragma unroll
    for (int i = 0; i < 4; ++i) bv[i] = *(const bf16x8*)(&Xl[boff[i]]);

    #pragma unroll
    for (int io = 0; io < 4; ++io)
      #pragma unroll
      for (int im = 0; im < 4; ++im)
        acc[io][im] = __builtin_amdgcn_mfma_f32_16x16x32_bf16(av[io], bv[im], acc[io][im], 0, 0, 0);
  }

  // Epilogue: D row=(quad*4+r) -> o, col=(lane&15) -> m. out[n][o][oh][ow], spatial==m%2916.
  #pragma unroll
  for (int im = 0; im < 4; ++im) {
    int m  = m0 + wm + im*16 + col;
    int n  = m / OHW;
    int rm = m - n*OHW;
    float* obase = out + n*(OC*OHW) + rm;
    #pragma unroll
    for (int io = 0; io < 4; ++io) {
      int orow = ob*BO + wo + io*16 + quad*4;
      #pragma unroll
      for (int r = 0; r < 4; ++r)
        obase[(orow + r)*OHW] = acc[io][im][r];
    }
  }
}

extern "C" void kernel_launch(void* const* d_in, const int* in_sizes, int n_in,
                              void* d_out, int out_size, void* d_ws, size_t ws_size,
                              hipStream_t stream) {
  const float* x = (const float*)d_in[0];   // [32,256,56,56] fp32
  const float* w = (const float*)d_in[1];   // [256,256,3,3] fp32
  float* out = (float*)d_out;               // [32,256,54,54] fp32

  repack_w<<<dim3((2*KSTEPS*BO*BK)/256), 256, 0, stream>>>(w);
  xform_x <<<dim3(HW/64, NB), 256, 0, stream>>>(x);
  bconv_gemm<<<dim3(MBLOCKS, 2), 256, 0, stream>>>(out);
}

// Round 2
// 358.641 us; speedup vs baseline: 1.0359x; 1.0359x over previous
//
#include <hip/hip_runtime.h>
#include <cstdint>

// Problem constants
#define NB 32
#define IC 256
#define OC 256
#define H 56
#define WIDTH 56
#define OH 54
#define OW 54
#define HW (H*WIDTH)          // 3136
#define OHW (OH*OW)           // 2916
#define KTOT 2304             // 9 * 256, k = (kh*3+kw)*256 + c
#define M_TOT (NB*OHW)        // 93312

// GEMM tiling
#define BM 128                // spatial tile (D cols)
#define BO 128                // out-channel tile (D rows)
#define BK 32
#define KSTEPS (KTOT/BK)      // 72
#define MBLOCKS (M_TOT/BM)    // 729

// Static device scratch:
// weights pre-tiled as the per-K-step LDS images: [ob(2)][step(72)][o'(128)][kc(32)] bf16 bits
__device__ __align__(16) unsigned short g_qwt[2*KSTEPS*BO*BK];
// x as NHWC bf16: [n][ih][iw][c]
__device__ __align__(16) unsigned short g_xq[NB*HW*IC];

typedef __bf16 bf16x8 __attribute__((ext_vector_type(8)));
typedef float  f32x4  __attribute__((ext_vector_type(4)));

typedef __attribute__((address_space(1))) const unsigned int gas_u32;
typedef __attribute__((address_space(3))) unsigned int las_u32;
__device__ __forceinline__ void async_copy16(const void* g, void* l) {
  // global -> LDS direct copy, 16 B per lane; LDS dst = wave-uniform base + lane*16
  __builtin_amdgcn_global_load_lds((gas_u32*)g, (las_u32*)l, 16, 0, 0);
}

__device__ inline unsigned short f32_bf16(float f) {
  union { float f; unsigned int u; } v; v.f = f;
  unsigned int u = v.u;
  return (unsigned short)((u + 0x7FFFu + ((u >> 16) & 1u)) >> 16);  // RNE
}

// ---- Kernel 1: binarize + pre-tile weights -------------------------------
// w layout: [o][c][kh][kw] fp32.  g_qwt[L], L linear over [ob][step][r][kc].
__global__ __launch_bounds__(256) void repack_w(const float* __restrict__ w) {
  int L = blockIdx.x * 256 + threadIdx.x;           // < 589824
  int ob  = (L >= KSTEPS*BO*BK) ? 1 : 0;
  int rem = L - ob*(KSTEPS*BO*BK);
  int step = rem >> 12;                             // /4096
  int r    = (rem >> 5) & 127;
  int kc   = rem & 31;
  int o = ob*BO + r;
  int k = step*BK + kc;
  int pos = k >> 8;                                 // kh*3+kw
  int c   = k & 255;
  int kh = pos / 3;
  int kw = pos - kh*3;
  float v = w[o*2304 + c*9 + kh*3 + kw];
  unsigned short s = (v > 0.f) ? 0x3F80u : ((v < 0.f) ? 0xBF80u : 0u);  // sign() in bf16
  g_qwt[L] = s;
}

// ---- Kernel 2: x NCHW fp32 -> NHWC bf16, fully vectorized ----------------
// Tile: 64 hw x 256 c. Reads float4 (coalesced), LDS transpose, writes uint4
// (each wave stores 1024 B contiguous).
__global__ __launch_bounds__(256) void xform_x(const float* __restrict__ x) {
  __shared__ unsigned short tile[64][IC + 8];       // row stride 528 B (16B-aligned)
  const int t   = threadIdx.x;
  const int n   = blockIdx.y;
  const int hw0 = blockIdx.x * 64;
  const int cl  = t >> 4;                           // 0..15
  const int hl  = (t & 15) * 4;                     // 0..60
  #pragma unroll 4
  for (int j = 0; j < 16; ++j) {
    int c = j*16 + cl;
    const float4 v = *(const float4*)(&x[(n*IC + c)*HW + hw0 + hl]);
    tile[hl+0][c] = f32_bf16(v.x);
    tile[hl+1][c] = f32_bf16(v.y);
    tile[hl+2][c] = f32_bf16(v.z);
    tile[hl+3][c] = f32_bf16(v.w);
  }
  __syncthreads();
  const int ch = (t & 31) * 8;                      // c chunk (8 bf16 = 16 B)
  const int hr = t >> 5;                            // 0..7
  #pragma unroll
  for (int p = 0; p < 8; ++p) {
    int hwi = p*8 + hr;
    *(uint4*)(&g_xq[(n*HW + hw0 + hwi)*IC + ch]) = *(const uint4*)(&tile[hwi][ch]);
  }
}

// ---- Kernel 3: implicit-GEMM binary conv, D[o][m] ------------------------
// A-operand = weights (rows o), B-operand = im2col(x) (cols m).
// Staging via global_load_lds dwordx4 (async, no VGPR round-trip).
__global__ __launch_bounds__(256) void bconv_gemm(float* __restrict__ out) {
  __shared__ __align__(16) unsigned short Wl[BO*BK];   // [o'][kc] 8 KB
  __shared__ __align__(16) unsigned short Xl[BM*BK];   // [m'][kc] 8 KB
  const int t  = threadIdx.x;
  const int m0 = blockIdx.x * BM;
  const int ob = blockIdx.y;

  // X staging: 512 16B-chunks per tile; thread t owns chunks t and t+256.
  // chunk q -> row i=q>>2 (m = m0+i), k-offset (q&3)*8. Spatial base fixed across K loop.
  int soff[2];
  #pragma unroll
  for (int hh = 0; hh < 2; ++hh) {
    int q = t + hh*256;
    int m = m0 + (q >> 2);
    int n  = m / OHW;
    int rm = m - n*OHW;
    int oh = rm / OW;
    int ow = rm - oh*OW;
    soff[hh] = ((n*H + oh)*WIDTH + ow)*IC + (q & 3)*8;
  }
  const unsigned short* wsrc = g_qwt + ob*(KSTEPS*BO*BK);

  const int lane = t & 63;
  const int wv   = t >> 6;
  const int col  = lane & 15;
  const int quad = lane >> 4;
  const int wo = (wv & 1) * 64;     // wave's o-offset in block tile
  const int wm = (wv >> 1) * 64;    // wave's m-offset in block tile
  int aoff[4], boff[4];
  #pragma unroll
  for (int i = 0; i < 4; ++i) {
    aoff[i] = (wo + i*16 + col)*BK + quad*8;   // A[m=lane&15][k=quad*8+j]
    boff[i] = (wm + i*16 + col)*BK + quad*8;   // B[k=quad*8+j][n=lane&15]
  }

  f32x4 acc[4][4];
  #pragma unroll
  for (int io = 0; io < 4; ++io)
    #pragma unroll
    for (int im = 0; im < 4; ++im)
      acc[io][im] = (f32x4){0.f, 0.f, 0.f, 0.f};

  for (int step = 0; step < KSTEPS; ++step) {
    const int k0  = step * BK;
    const int pos = k0 >> 8;           // uniform scalar
    const int c0  = k0 & 255;
    const int kh  = pos / 3;
    const int kw  = pos - kh*3;
    const int sk  = (kh*WIDTH + kw)*IC + c0;

    __syncthreads();
    // W tile: linear async copy (pre-tiled in global); LDS order == lane order
    async_copy16(&wsrc[step*(BO*BK) + t*8],         &Wl[t*8]);
    async_copy16(&wsrc[step*(BO*BK) + (t+256)*8],   &Wl[(t+256)*8]);
    // X tile: im2col gather, 16B per chunk, 16B-aligned
    async_copy16(&g_xq[soff[0] + sk],               &Xl[t*8]);
    async_copy16(&g_xq[soff[1] + sk],               &Xl[(t+256)*8]);
    __syncthreads();   // compiler emits s_waitcnt vmcnt(0) before s_barrier

    bf16x8 av[4], bv[4];
    #pragma unroll
    for (int i = 0; i < 4; ++i) av[i] = *(const bf16x8*)(&Wl[aoff[i]]);
    #pragma unroll
    for (int i = 0; i < 4; ++i) bv[i] = *(const bf16x8*)(&Xl[boff[i]]);

    #pragma unroll
    for (int io = 0; io < 4; ++io)
      #pragma unroll
      for (int im = 0; im < 4; ++im)
        acc[io][im] = __builtin_amdgcn_mfma_f32_16x16x32_bf16(av[io], bv[im], acc[io][im], 0, 0, 0);
  }

  // Epilogue: D row=(quad*4+r) -> o, col=(lane&15) -> m. out[n][o][oh][ow], spatial==m%2916.
  #pragma unroll
  for (int im = 0; im < 4; ++im) {
    int m  = m0 + wm + im*16 + col;
    int n  = m / OHW;
    int rm = m - n*OHW;
    float* obase = out + n*(OC*OHW) + rm;
    #pragma unroll
    for (int io = 0; io < 4; ++io) {
      int orow = ob*BO + wo + io*16 + quad*4;
      #pragma unroll
      for (int r = 0; r < 4; ++r)
        obase[(orow + r)*OHW] = acc[io][im][r];
    }
  }
}

extern "C" void kernel_launch(void* const* d_in, const int* in_sizes, int n_in,
                              void* d_out, int out_size, void* d_ws, size_t ws_size,
                              hipStream_t stream) {
  const float* x = (const float*)d_in[0];   // [32,256,56,56] fp32
  const float* w = (const float*)d_in[1];   // [256,256,3,3] fp32
  float* out = (float*)d_out;               // [32,256,54,54] fp32

  repack_w<<<dim3((2*KSTEPS*BO*BK)/256), 256, 0, stream>>>(w);
  xform_x <<<dim3(HW/64, NB), 256, 0, stream>>>(x);
  bconv_gemm<<<dim3(MBLOCKS, 2), 256, 0, stream>>>(out);
}